// Round 17
// baseline (191.474 us; speedup 1.0000x reference)
//
#include <hip/hip_runtime.h>
#include <math.h>

#define B_ 2
#define L_ 2048
#define C_ 768
#define H_ 12
#define D_ 64
#define M_ (B_ * L_)          // 4096
#define MAXLOG 4.605170185988091f   // log(100)

typedef __bf16 bf16;
typedef __bf16 bf16x4 __attribute__((ext_vector_type(4)));
typedef __bf16 bf16x8 __attribute__((ext_vector_type(8)));
typedef _Float16 f16;
typedef _Float16 f16x4 __attribute__((ext_vector_type(4)));
typedef _Float16 f16x8 __attribute__((ext_vector_type(8)));
typedef float  f32x4  __attribute__((ext_vector_type(4)));
typedef short  s16x4  __attribute__((ext_vector_type(4)));

// workspace element counts
#define SZ_  ((size_t)B_ * H_ * L_ * D_)   // 3,145,728 (q,k,vt each)
#define MC_  ((size_t)M_ * C_)             // 3,145,728 (x / ao)
#define WQ_  ((size_t)3 * C_ * C_)         // 1,769,472 (W_qkv)
#define WP_  ((size_t)C_ * C_)             //   589,824 (W_proj)

// K=16 bf16 MFMA. S^T accumulator layout (row=4*quad+reg, col=lane&15) equals
// this op's B-fragment layout, so P^T feeds PV directly from registers.
static __device__ __forceinline__ f32x4 mfma16(bf16x4 a, bf16x4 b, f32x4 c) {
#if __has_builtin(__builtin_amdgcn_mfma_f32_16x16x16_bf16)
    return __builtin_amdgcn_mfma_f32_16x16x16_bf16(a, b, c, 0, 0, 0);
#elif __has_builtin(__builtin_amdgcn_mfma_f32_16x16x16bf16_1k)
    return __builtin_amdgcn_mfma_f32_16x16x16bf16_1k(*(s16x4*)&a, *(s16x4*)&b, c, 0, 0, 0);
#else
    f32x4 d;
    asm("v_mfma_f32_16x16x16_bf16 %0, %1, %2, %3" : "=v"(d) : "v"(a), "v"(b), "v"(c));
    return d;
#endif
}

// 16B async global->LDS stage (GEMMs only; LDS dest linear in lane).
static __device__ __forceinline__ void stage16(const void* gsrc, void* ldst) {
#if __has_builtin(__builtin_amdgcn_global_load_lds)
    __builtin_amdgcn_global_load_lds(
        (const __attribute__((address_space(1))) unsigned int*)gsrc,
        (__attribute__((address_space(3))) unsigned int*)ldst, 16, 0, 0);
#else
    *(bf16x8*)ldst = *(const bf16x8*)gsrc;
#endif
}

// ---------------------------------------------------------------------------
// Kernel 0: fused prep (x/W_qkv -> bf16, W_proj -> single f16).
// ---------------------------------------------------------------------------
__global__ __launch_bounds__(256) void prep(
    const float4* __restrict__ x, const float4* __restrict__ Wq,
    const float4* __restrict__ Wp,
    bf16* __restrict__ xb, bf16* __restrict__ wqb,
    f16* __restrict__ Wf)
{
    const int X4 = (int)(MC_ / 4);
    const int W4 = (int)(WQ_ / 4);
    const int S4 = (int)(WP_ / 4);
    const int total = X4 + W4 + S4;

    const int i0 = blockIdx.x * 256 + threadIdx.x;
    const int stride = gridDim.x * 256;
    for (int i = i0; i < total; i += stride) {
        if (i < X4) {
            const float4 v = x[i];
            bf16x4 o; o[0]=(bf16)v.x; o[1]=(bf16)v.y; o[2]=(bf16)v.z; o[3]=(bf16)v.w;
            *(bf16x4*)&xb[(size_t)i * 4] = o;
        } else if (i < X4 + W4) {
            const int j = i - X4;
            const float4 v = Wq[j];
            bf16x4 o; o[0]=(bf16)v.x; o[1]=(bf16)v.y; o[2]=(bf16)v.z; o[3]=(bf16)v.w;
            *(bf16x4*)&wqb[(size_t)j * 4] = o;
        } else {
            const int j = i - X4 - W4;
            const float4 v = Wp[j];
            f16x4 o; o[0]=(f16)v.x; o[1]=(f16)v.y; o[2]=(f16)v.z; o[3]=(f16)v.w;
            *(f16x4*)&Wf[(size_t)j * 4] = o;
        }
    }
}

// ---------------------------------------------------------------------------
// Kernel 1: QKV GEMM v2 (R12: 128x128 tile, 2 heads/block).
// ---------------------------------------------------------------------------
__global__ __launch_bounds__(256, 3) void qkv_mfma(
    const bf16* __restrict__ A, const bf16* __restrict__ W,
    const float* __restrict__ bias, const float* __restrict__ sml,
    bf16* __restrict__ qb, bf16* __restrict__ kb, bf16* __restrict__ vtb)
{
    __shared__ __align__(16) bf16 As[128][64];   // 16 KB, linear
    __shared__ __align__(16) bf16 Bs[128][64];   // 16 KB, linear

    const int t    = threadIdx.x;
    const int w    = t >> 6;
    const int lane = t & 63;
    const int quad = lane >> 4;
    const int c    = lane & 15;
    const int m0   = blockIdx.x * 128;
    const int n0   = blockIdx.y * 128;

    const int sr = t >> 3;           // 0..31
    const int sc = t & 7;
    const int sx = sc ^ (sr & 7);    // pre-swizzled source chunk

    f32x4 acc[2][8];
    #pragma unroll
    for (int mt = 0; mt < 2; ++mt)
        #pragma unroll
        for (int nt = 0; nt < 8; ++nt) acc[mt][nt] = (f32x4){0.f,0.f,0.f,0.f};

    for (int kt = 0; kt < C_; kt += 64) {
        __syncthreads();   // prev iter's LDS reads complete before overwrite
        #pragma unroll
        for (int p = 0; p < 4; ++p)
            stage16(&A[(size_t)(m0 + 32 * p + sr) * C_ + kt + 8 * sx],
                    (char*)&As[0][0] + (p * 256 + t) * 16);
        #pragma unroll
        for (int p = 0; p < 4; ++p)
            stage16(&W[(size_t)(n0 + 32 * p + sr) * C_ + kt + 8 * sx],
                    (char*)&Bs[0][0] + (p * 256 + t) * 16);
        __syncthreads();   // vmcnt drain: staged tiles ready

        #pragma unroll
        for (int ks = 0; ks < 2; ++ks) {
            const int rchunk = ((4 * ks + quad) ^ (c & 7)) * 16;
            bf16x8 bfr[8];
            #pragma unroll
            for (int nt = 0; nt < 8; ++nt)
                bfr[nt] = *(const bf16x8*)((const char*)&Bs[0][0]
                          + (size_t)(nt * 16 + c) * 128 + rchunk);
            #pragma unroll
            for (int mt = 0; mt < 2; ++mt) {
                const bf16x8 a = *(const bf16x8*)((const char*)&As[0][0]
                                 + (size_t)(w * 32 + mt * 16 + c) * 128 + rchunk);
                #pragma unroll
                for (int nt = 0; nt < 8; ++nt)
                    acc[mt][nt] = __builtin_amdgcn_mfma_f32_16x16x32_bf16(a, bfr[nt], acc[mt][nt], 0, 0, 0);
            }
        }
    }

    const int three = blockIdx.y / 6;          // 768 % 128 == 0: no straddle
    const int hbase = (blockIdx.y % 6) * 2;    // first head of this block
    const int bidx  = m0 >> 11;
    const int l0    = (m0 & (L_ - 1)) + w * 32;

    if (three < 2) {
        bf16* dst = (three == 0) ? qb : kb;
        float scale[2];
        #pragma unroll
        for (int hp = 0; hp < 2; ++hp)
            scale[hp] = (three == 0) ? expf(fminf(sml[hbase + hp], MAXLOG)) : 1.0f;
        #pragma unroll
        for (int mt = 0; mt < 2; ++mt) {
            float val[8][4];
            float ss[2][4] = {{0.f,0.f,0.f,0.f},{0.f,0.f,0.f,0.f}};
            #pragma unroll
            for (int nt = 0; nt < 8; ++nt) {
                const float bb = bias[n0 + nt * 16 + c];
                #pragma unroll
                for (int reg = 0; reg < 4; ++reg) {
                    const float v = acc[mt][nt][reg] + bb;
                    val[nt][reg] = v;
                    ss[nt >> 2][reg] += v * v;
                }
            }
            #pragma unroll
            for (int hp = 0; hp < 2; ++hp)
                #pragma unroll
                for (int reg = 0; reg < 4; ++reg) {
                    float s = ss[hp][reg];
                    #pragma unroll
                    for (int off = 1; off < 16; off <<= 1) s += __shfl_xor(s, off, 16);
                    const float inv = scale[hp] / fmaxf(sqrtf(s), 1e-12f);
                    const int l = l0 + mt * 16 + quad * 4 + reg;
                    const int h = hbase + hp;
                    #pragma unroll
                    for (int nt4 = 0; nt4 < 4; ++nt4)
                        dst[((size_t)(bidx * H_ + h) * L_ + l) * D_ + nt4 * 16 + c] =
                            (bf16)(val[hp * 4 + nt4][reg] * inv);
                }
        }
    } else {
        #pragma unroll
        for (int mt = 0; mt < 2; ++mt)
            #pragma unroll
            for (int nt = 0; nt < 8; ++nt) {
                const int h = hbase + (nt >> 2);
                const int d = (nt & 3) * 16 + c;
                const float bb = bias[n0 + nt * 16 + c];
                const int l = l0 + mt * 16 + quad * 4;
                bf16x4 ov;
                #pragma unroll
                for (int reg = 0; reg < 4; ++reg) ov[reg] = (bf16)(acc[mt][nt][reg] + bb);
                *(bf16x4*)&vtb[((size_t)(bidx * H_ + h) * D_ + d) * L_ + l] = ov;
            }
    }
}

// ---------------------------------------------------------------------------
// Kernel 2: flash attention — v7 structure (plateau); f16 hi/lo epilogue.
// ---------------------------------------------------------------------------
__global__ __launch_bounds__(256, 3) void flash_mfma(
    const bf16* __restrict__ q, const bf16* __restrict__ k,
    const bf16* __restrict__ vt, const float* __restrict__ bias,
    const float* __restrict__ sml,
    f16* __restrict__ aoh, f16* __restrict__ aol)
{
    __shared__ __align__(16) bf16 Ks0 [64][72];
    __shared__ __align__(16) bf16 Ks1 [64][72];
    __shared__ __align__(16) bf16 Vts0[64][72];
    __shared__ __align__(16) bf16 Vts1[64][72];

    const int t    = threadIdx.x;
    const int w    = t >> 6;
    const int lane = t & 63;
    const int quad = lane >> 4;
    const int c    = lane & 15;
    const int q0   = blockIdx.x * 64;
    const int bh   = blockIdx.y;
    const int h    = bh % H_;
    const int b    = bh / H_;
    const size_t base  = (size_t)bh * L_ * D_;
    const size_t vbase = (size_t)bh * D_ * L_;
    const int qrow = q0 + w * 16 + c;      // this lane's q index (column of S^T)

    const float FMAX = expf(fminf(sml[h], MAXLOG)) + 8.0f;

    // Q B-fragments straight from global, held for the whole sweep.
    bf16x8 qf[2];
    qf[0] = *(const bf16x8*)&q[base + (size_t)qrow * D_ + quad * 8];
    qf[1] = *(const bf16x8*)&q[base + (size_t)qrow * D_ + 32 + quad * 8];

    // staging indices (coalesced b128)
    const int r0  = t >> 3,         c00 = (t & 7) * 8;
    const int r1  = (t + 256) >> 3, c01 = ((t + 256) & 7) * 8;

    const size_t brow = (size_t)qrow * L_ + 4 * quad;

    float l_acc = 0.f;
    f32x4 o[4];
    #pragma unroll
    for (int dt = 0; dt < 4; ++dt) o[dt] = (f32x4){0.f, 0.f, 0.f, 0.f};

    bf16x8 kreg[2], vreg[2];
    f32x4  bregA[4], bregB[4];

    // prologue: tile 0 -> regs -> LDS buf0; tile 1 -> regs; bias 0/1 -> regs
    kreg[0] = *(const bf16x8*)&k [base  + (size_t)r0 * D_ + c00];
    kreg[1] = *(const bf16x8*)&k [base  + (size_t)r1 * D_ + c01];
    vreg[0] = *(const bf16x8*)&vt[vbase + (size_t)r0 * L_ + c00];
    vreg[1] = *(const bf16x8*)&vt[vbase + (size_t)r1 * L_ + c01];
    #pragma unroll
    for (int s = 0; s < 4; ++s)
        bregA[s] = *(const f32x4*)&bias[brow + 16 * s];

    *(bf16x8*)&Ks0 [r0][c00] = kreg[0];
    *(bf16x8*)&Ks0 [r1][c01] = kreg[1];
    *(bf16x8*)&Vts0[r0][c00] = vreg[0];
    *(bf16x8*)&Vts0[r1][c01] = vreg[1];

    kreg[0] = *(const bf16x8*)&k [base  + (size_t)(64 + r0) * D_ + c00];
    kreg[1] = *(const bf16x8*)&k [base  + (size_t)(64 + r1) * D_ + c01];
    vreg[0] = *(const bf16x8*)&vt[vbase + (size_t)r0 * L_ + 64 + c00];
    vreg[1] = *(const bf16x8*)&vt[vbase + (size_t)r1 * L_ + 64 + c01];
    #pragma unroll
    for (int s = 0; s < 4; ++s)
        bregB[s] = *(const f32x4*)&bias[brow + 64 + 16 * s];
    __syncthreads();

// One 64-k tile: stage tile IT+1 from regs, prefetch tile IT+2 into regs,
// compute tile IT, single barrier at the end.
#define FSTEP(KS_C, VT_C, KS_N, VT_N, BC, IT) do {                               \
    if ((IT) + 1 < 32) {                                                         \
        *(bf16x8*)&KS_N [r0][c00] = kreg[0];                                     \
        *(bf16x8*)&KS_N [r1][c01] = kreg[1];                                     \
        *(bf16x8*)&VT_N [r0][c00] = vreg[0];                                     \
        *(bf16x8*)&VT_N [r1][c01] = vreg[1];                                     \
    }                                                                            \
    f32x4 st[4];                                                                 \
    _Pragma("unroll") for (int s = 0; s < 4; ++s) st[s] = BC[s];                 \
    if ((IT) + 2 < 32) {                                                         \
        const int kp = ((IT) + 2) * 64;                                          \
        kreg[0] = *(const bf16x8*)&k [base  + (size_t)(kp + r0) * D_ + c00];     \
        kreg[1] = *(const bf16x8*)&k [base  + (size_t)(kp + r1) * D_ + c01];     \
        vreg[0] = *(const bf16x8*)&vt[vbase + (size_t)r0 * L_ + kp + c00];       \
        vreg[1] = *(const bf16x8*)&vt[vbase + (size_t)r1 * L_ + kp + c01];       \
        _Pragma("unroll") for (int s = 0; s < 4; ++s)                            \
            BC[s] = *(const f32x4*)&bias[brow + kp + 16 * s];                    \
    }                                                                            \
    _Pragma("unroll") for (int ks = 0; ks < 2; ++ks)                             \
        _Pragma("unroll") for (int s = 0; s < 4; ++s) {                          \
            const bf16x8 kf = *(const bf16x8*)&KS_C[s*16 + c][ks*32 + quad*8];   \
            st[s] = __builtin_amdgcn_mfma_f32_16x16x32_bf16(kf, qf[ks], st[s], 0, 0, 0); \
        }                                                                        \
    bf16x4 pf[4];                                                                \
    _Pragma("unroll") for (int s = 0; s < 4; ++s)                                \
        _Pragma("unroll") for (int r = 0; r < 4; ++r) {                          \
            const float pv = __expf(st[s][r] - FMAX);                            \
            l_acc += pv;                                                         \
            pf[s][r] = (bf16)pv;                                                 \
        }                                                                        \
    _Pragma("unroll") for (int s = 0; s < 4; ++s)                                \
        _Pragma("unroll") for (int dt = 0; dt < 4; ++dt) {                       \
            const bf16x4 vfr = *(const bf16x4*)&VT_C[dt*16 + c][16*s + 4*quad];  \
            o[dt] = mfma16(vfr, pf[s], o[dt]);                                   \
        }                                                                        \
    __syncthreads();                                                             \
} while (0)

    for (int it = 0; it < 32; it += 2) {
        FSTEP(Ks0, Vts0, Ks1, Vts1, bregA, it);
        FSTEP(Ks1, Vts1, Ks0, Vts0, bregB, it + 1);
    }
#undef FSTEP

    // l: lane holds k-rows 4*quad+0..3 of every tile; reduce across quads.
    float rs = l_acc;
    rs += __shfl_xor(rs, 16);
    rs += __shfl_xor(rs, 32);
    const float linv = 1.0f / rs;

    const size_t obase = ((size_t)(b * L_ + qrow)) * C_ + h * 64;
    #pragma unroll
    for (int dt = 0; dt < 4; ++dt) {
        f16x4 hv, lv;
        #pragma unroll
        for (int r = 0; r < 4; ++r) {
            const float v = o[dt][r] * linv;
            hv[r] = (f16)v;
            lv[r] = (f16)(v - (float)hv[r]);
        }
        *(f16x4*)&aoh[obase + dt * 16 + 4 * quad] = hv;
        *(f16x4*)&aol[obase + dt * 16 + 4 * quad] = lv;
    }
}

// ---------------------------------------------------------------------------
// Kernel 3: projection GEMM v3 (R15 — best measured): f16 2-MFMA path,
//   BM=128 BN=64, grid 32x12. A = f16 hi/lo pair, W = single f16.
// ---------------------------------------------------------------------------
__global__ __launch_bounds__(256) void proj_mfma(
    const f16* __restrict__ Ahg, const f16* __restrict__ Alg,
    const f16* __restrict__ Wfg,
    const float* __restrict__ bias, float* __restrict__ outp)
{
    __shared__ __align__(16) f16 Ah[128][64];   // 16 KB
    __shared__ __align__(16) f16 Al[128][64];   // 16 KB
    __shared__ __align__(16) f16 Wf[64][64];    //  8 KB

    const int t    = threadIdx.x;
    const int w    = t >> 6;
    const int lane = t & 63;
    const int quad = lane >> 4;
    const int c    = lane & 15;
    const int m0   = blockIdx.x * 128;
    const int n0   = blockIdx.y * 64;

    const int sr = t >> 3;           // 0..31
    const int sc = t & 7;
    const int sx = sc ^ (sr & 7);

    f32x4 acc[2][4];
    #pragma unroll
    for (int mt = 0; mt < 2; ++mt)
        #pragma unroll
        for (int nt = 0; nt < 4; ++nt) acc[mt][nt] = (f32x4){0.f,0.f,0.f,0.f};

    for (int kt = 0; kt < C_; kt += 64) {
        __syncthreads();
        #pragma unroll
        for (int p = 0; p < 4; ++p) {
            const size_t ga = (size_t)(m0 + 32 * p + sr) * C_ + kt + 8 * sx;
            const int    lo = (p * 256 + t) * 16;
            stage16(&Ahg[ga], (char*)&Ah[0][0] + lo);
            stage16(&Alg[ga], (char*)&Al[0][0] + lo);
        }
        #pragma unroll
        for (int p = 0; p < 2; ++p) {
            const size_t gb = (size_t)(n0 + 32 * p + sr) * C_ + kt + 8 * sx;
            const int    lo = (p * 256 + t) * 16;
            stage16(&Wfg[gb], (char*)&Wf[0][0] + lo);
        }
        __syncthreads();

        #pragma unroll
        for (int ks = 0; ks < 2; ++ks) {
            const int rchunk = ((4 * ks + quad) ^ (c & 7)) * 16;
            f16x8 wf[4];
            #pragma unroll
            for (int nt = 0; nt < 4; ++nt)
                wf[nt] = *(const f16x8*)((const char*)&Wf[0][0]
                         + (size_t)(nt * 16 + c) * 128 + rchunk);
            #pragma unroll
            for (int mt = 0; mt < 2; ++mt) {
                const f16x8 ah = *(const f16x8*)((const char*)&Ah[0][0]
                                 + (size_t)(w * 32 + mt * 16 + c) * 128 + rchunk);
                const f16x8 al = *(const f16x8*)((const char*)&Al[0][0]
                                 + (size_t)(w * 32 + mt * 16 + c) * 128 + rchunk);
                #pragma unroll
                for (int nt = 0; nt < 4; ++nt) {
                    acc[mt][nt] = __builtin_amdgcn_mfma_f32_16x16x32_f16(ah, wf[nt], acc[mt][nt], 0, 0, 0);
                    acc[mt][nt] = __builtin_amdgcn_mfma_f32_16x16x32_f16(al, wf[nt], acc[mt][nt], 0, 0, 0);
                }
            }
        }
    }

    #pragma unroll
    for (int mt = 0; mt < 2; ++mt)
        #pragma unroll
        for (int nt = 0; nt < 4; ++nt) {
            const int col = n0 + nt * 16 + c;
            const float bb = bias[col];
            #pragma unroll
            for (int reg = 0; reg < 4; ++reg) {
                const int row = m0 + w * 32 + mt * 16 + quad * 4 + reg;
                outp[(size_t)row * C_ + col] = acc[mt][nt][reg] + bb;
            }
        }
}

// ---------------------------------------------------------------------------
extern "C" void kernel_launch(void* const* d_in, const int* in_sizes, int n_in,
                              void* d_out, int out_size, void* d_ws, size_t ws_size,
                              hipStream_t stream)
{
    const float* x         = (const float*)d_in[0];
    const float* attn_bias = (const float*)d_in[1];
    const float* W_qkv     = (const float*)d_in[2];
    const float* b_qkv     = (const float*)d_in[3];
    const float* sml       = (const float*)d_in[4];
    const float* W_proj    = (const float*)d_in[5];
    const float* b_proj    = (const float*)d_in[6];
    float* out = (float*)d_out;

    // ws layout (2-byte elements): qb,kb,vtb | aoh,aol (f16) | Wf (f16) | pad | xb | wqb
    bf16* qb  = (bf16*)d_ws;
    bf16* kb  = qb  + SZ_;
    bf16* vtb = kb  + SZ_;
    f16*  aoh = (f16*)(vtb + SZ_);
    f16*  aol = aoh + MC_;
    f16*  Wf  = aol + MC_;
    bf16* xb  = (bf16*)(Wf + 2 * WP_);   // (second WP_ slot unused, layout stability)
    bf16* wqb = xb  + MC_;

    // 0) fused prep: cvt x/W_qkv to bf16, W_proj to single f16
    prep<<<2048, 256, 0, stream>>>(
        (const float4*)x, (const float4*)W_qkv, (const float4*)W_proj,
        xb, wqb, Wf);

    // 1) QKV GEMM v2: 128x128 tile (2 heads/block), grid 32x18
    qkv_mfma<<<dim3(M_ / 128, (3 * C_) / 128), 256, 0, stream>>>(
        xb, wqb, b_qkv, sml, qb, kb, vtb);

    // 2) flash attention (v7 structure; f16 hi/lo epilogue)
    flash_mfma<<<dim3(L_ / 64, B_ * H_), 256, 0, stream>>>(
        qb, kb, vtb, attn_bias, sml, aoh, aol);

    // 3) projection GEMM v3 (R15 best): f16 2-MFMA, BM=128 BN=64, grid 32x12
    proj_mfma<<<dim3(M_ / 128, C_ / 64), 256, 0, stream>>>(
        aoh, aol, Wf, b_proj, out);
}

// Round 18
// 189.270 us; speedup vs baseline: 1.0116x; 1.0116x over previous
//
#include <hip/hip_runtime.h>
#include <math.h>

#define B_ 2
#define L_ 2048
#define C_ 768
#define H_ 12
#define D_ 64
#define M_ (B_ * L_)          // 4096
#define MAXLOG 4.605170185988091f   // log(100)

typedef __bf16 bf16;
typedef __bf16 bf16x4 __attribute__((ext_vector_type(4)));
typedef __bf16 bf16x8 __attribute__((ext_vector_type(8)));
typedef _Float16 f16;
typedef _Float16 f16x4 __attribute__((ext_vector_type(4)));
typedef _Float16 f16x8 __attribute__((ext_vector_type(8)));
typedef float  f32x4  __attribute__((ext_vector_type(4)));
typedef short  s16x4  __attribute__((ext_vector_type(4)));

// workspace element counts
#define SZ_  ((size_t)B_ * H_ * L_ * D_)   // 3,145,728 (q,k,vt each)
#define MC_  ((size_t)M_ * C_)             // 3,145,728 (x / ao)
#define WQ_  ((size_t)3 * C_ * C_)         // 1,769,472 (W_qkv)
#define WP_  ((size_t)C_ * C_)             //   589,824 (W_proj)

// K=16 bf16 MFMA. S^T accumulator layout (row=4*quad+reg, col=lane&15) equals
// this op's B-fragment layout, so P^T feeds PV directly from registers.
static __device__ __forceinline__ f32x4 mfma16(bf16x4 a, bf16x4 b, f32x4 c) {
#if __has_builtin(__builtin_amdgcn_mfma_f32_16x16x16_bf16)
    return __builtin_amdgcn_mfma_f32_16x16x16_bf16(a, b, c, 0, 0, 0);
#elif __has_builtin(__builtin_amdgcn_mfma_f32_16x16x16bf16_1k)
    return __builtin_amdgcn_mfma_f32_16x16x16bf16_1k(*(s16x4*)&a, *(s16x4*)&b, c, 0, 0, 0);
#else
    f32x4 d;
    asm("v_mfma_f32_16x16x16_bf16 %0, %1, %2, %3" : "=v"(d) : "v"(a), "v"(b), "v"(c));
    return d;
#endif
}

// 16B async global->LDS stage (GEMMs only; LDS dest linear in lane).
static __device__ __forceinline__ void stage16(const void* gsrc, void* ldst) {
#if __has_builtin(__builtin_amdgcn_global_load_lds)
    __builtin_amdgcn_global_load_lds(
        (const __attribute__((address_space(1))) unsigned int*)gsrc,
        (__attribute__((address_space(3))) unsigned int*)ldst, 16, 0, 0);
#else
    *(bf16x8*)ldst = *(const bf16x8*)gsrc;
#endif
}

// ---------------------------------------------------------------------------
// Kernel 0: fused prep (x/W_qkv -> bf16, W_proj -> single f16).
// ---------------------------------------------------------------------------
__global__ __launch_bounds__(256) void prep(
    const float4* __restrict__ x, const float4* __restrict__ Wq,
    const float4* __restrict__ Wp,
    bf16* __restrict__ xb, bf16* __restrict__ wqb,
    f16* __restrict__ Wf)
{
    const int X4 = (int)(MC_ / 4);
    const int W4 = (int)(WQ_ / 4);
    const int S4 = (int)(WP_ / 4);
    const int total = X4 + W4 + S4;

    const int i0 = blockIdx.x * 256 + threadIdx.x;
    const int stride = gridDim.x * 256;
    for (int i = i0; i < total; i += stride) {
        if (i < X4) {
            const float4 v = x[i];
            bf16x4 o; o[0]=(bf16)v.x; o[1]=(bf16)v.y; o[2]=(bf16)v.z; o[3]=(bf16)v.w;
            *(bf16x4*)&xb[(size_t)i * 4] = o;
        } else if (i < X4 + W4) {
            const int j = i - X4;
            const float4 v = Wq[j];
            bf16x4 o; o[0]=(bf16)v.x; o[1]=(bf16)v.y; o[2]=(bf16)v.z; o[3]=(bf16)v.w;
            *(bf16x4*)&wqb[(size_t)j * 4] = o;
        } else {
            const int j = i - X4 - W4;
            const float4 v = Wp[j];
            f16x4 o; o[0]=(f16)v.x; o[1]=(f16)v.y; o[2]=(f16)v.z; o[3]=(f16)v.w;
            *(f16x4*)&Wf[(size_t)j * 4] = o;
        }
    }
}

// ---------------------------------------------------------------------------
// Kernel 1: QKV GEMM v2 (R12: 128x128 tile, 2 heads/block).
// ---------------------------------------------------------------------------
__global__ __launch_bounds__(256, 3) void qkv_mfma(
    const bf16* __restrict__ A, const bf16* __restrict__ W,
    const float* __restrict__ bias, const float* __restrict__ sml,
    bf16* __restrict__ qb, bf16* __restrict__ kb, bf16* __restrict__ vtb)
{
    __shared__ __align__(16) bf16 As[128][64];   // 16 KB, linear
    __shared__ __align__(16) bf16 Bs[128][64];   // 16 KB, linear

    const int t    = threadIdx.x;
    const int w    = t >> 6;
    const int lane = t & 63;
    const int quad = lane >> 4;
    const int c    = lane & 15;
    const int m0   = blockIdx.x * 128;
    const int n0   = blockIdx.y * 128;

    const int sr = t >> 3;           // 0..31
    const int sc = t & 7;
    const int sx = sc ^ (sr & 7);    // pre-swizzled source chunk

    f32x4 acc[2][8];
    #pragma unroll
    for (int mt = 0; mt < 2; ++mt)
        #pragma unroll
        for (int nt = 0; nt < 8; ++nt) acc[mt][nt] = (f32x4){0.f,0.f,0.f,0.f};

    for (int kt = 0; kt < C_; kt += 64) {
        __syncthreads();   // prev iter's LDS reads complete before overwrite
        #pragma unroll
        for (int p = 0; p < 4; ++p)
            stage16(&A[(size_t)(m0 + 32 * p + sr) * C_ + kt + 8 * sx],
                    (char*)&As[0][0] + (p * 256 + t) * 16);
        #pragma unroll
        for (int p = 0; p < 4; ++p)
            stage16(&W[(size_t)(n0 + 32 * p + sr) * C_ + kt + 8 * sx],
                    (char*)&Bs[0][0] + (p * 256 + t) * 16);
        __syncthreads();   // vmcnt drain: staged tiles ready

        #pragma unroll
        for (int ks = 0; ks < 2; ++ks) {
            const int rchunk = ((4 * ks + quad) ^ (c & 7)) * 16;
            bf16x8 bfr[8];
            #pragma unroll
            for (int nt = 0; nt < 8; ++nt)
                bfr[nt] = *(const bf16x8*)((const char*)&Bs[0][0]
                          + (size_t)(nt * 16 + c) * 128 + rchunk);
            #pragma unroll
            for (int mt = 0; mt < 2; ++mt) {
                const bf16x8 a = *(const bf16x8*)((const char*)&As[0][0]
                                 + (size_t)(w * 32 + mt * 16 + c) * 128 + rchunk);
                #pragma unroll
                for (int nt = 0; nt < 8; ++nt)
                    acc[mt][nt] = __builtin_amdgcn_mfma_f32_16x16x32_bf16(a, bfr[nt], acc[mt][nt], 0, 0, 0);
            }
        }
    }

    const int three = blockIdx.y / 6;          // 768 % 128 == 0: no straddle
    const int hbase = (blockIdx.y % 6) * 2;    // first head of this block
    const int bidx  = m0 >> 11;
    const int l0    = (m0 & (L_ - 1)) + w * 32;

    if (three < 2) {
        bf16* dst = (three == 0) ? qb : kb;
        float scale[2];
        #pragma unroll
        for (int hp = 0; hp < 2; ++hp)
            scale[hp] = (three == 0) ? expf(fminf(sml[hbase + hp], MAXLOG)) : 1.0f;
        #pragma unroll
        for (int mt = 0; mt < 2; ++mt) {
            float val[8][4];
            float ss[2][4] = {{0.f,0.f,0.f,0.f},{0.f,0.f,0.f,0.f}};
            #pragma unroll
            for (int nt = 0; nt < 8; ++nt) {
                const float bb = bias[n0 + nt * 16 + c];
                #pragma unroll
                for (int reg = 0; reg < 4; ++reg) {
                    const float v = acc[mt][nt][reg] + bb;
                    val[nt][reg] = v;
                    ss[nt >> 2][reg] += v * v;
                }
            }
            #pragma unroll
            for (int hp = 0; hp < 2; ++hp)
                #pragma unroll
                for (int reg = 0; reg < 4; ++reg) {
                    float s = ss[hp][reg];
                    #pragma unroll
                    for (int off = 1; off < 16; off <<= 1) s += __shfl_xor(s, off, 16);
                    const float inv = scale[hp] / fmaxf(sqrtf(s), 1e-12f);
                    const int l = l0 + mt * 16 + quad * 4 + reg;
                    const int h = hbase + hp;
                    #pragma unroll
                    for (int nt4 = 0; nt4 < 4; ++nt4)
                        dst[((size_t)(bidx * H_ + h) * L_ + l) * D_ + nt4 * 16 + c] =
                            (bf16)(val[hp * 4 + nt4][reg] * inv);
                }
        }
    } else {
        #pragma unroll
        for (int mt = 0; mt < 2; ++mt)
            #pragma unroll
            for (int nt = 0; nt < 8; ++nt) {
                const int h = hbase + (nt >> 2);
                const int d = (nt & 3) * 16 + c;
                const float bb = bias[n0 + nt * 16 + c];
                const int l = l0 + mt * 16 + quad * 4;
                bf16x4 ov;
                #pragma unroll
                for (int reg = 0; reg < 4; ++reg) ov[reg] = (bf16)(acc[mt][nt][reg] + bb);
                *(bf16x4*)&vtb[((size_t)(bidx * H_ + h) * D_ + d) * L_ + l] = ov;
            }
    }
}

// ---------------------------------------------------------------------------
// Kernel 2: flash attention — v7 structure (plateau); f16 hi/lo epilogue.
// ---------------------------------------------------------------------------
__global__ __launch_bounds__(256, 3) void flash_mfma(
    const bf16* __restrict__ q, const bf16* __restrict__ k,
    const bf16* __restrict__ vt, const float* __restrict__ bias,
    const float* __restrict__ sml,
    f16* __restrict__ aoh, f16* __restrict__ aol)
{
    __shared__ __align__(16) bf16 Ks0 [64][72];
    __shared__ __align__(16) bf16 Ks1 [64][72];
    __shared__ __align__(16) bf16 Vts0[64][72];
    __shared__ __align__(16) bf16 Vts1[64][72];

    const int t    = threadIdx.x;
    const int w    = t >> 6;
    const int lane = t & 63;
    const int quad = lane >> 4;
    const int c    = lane & 15;
    const int q0   = blockIdx.x * 64;
    const int bh   = blockIdx.y;
    const int h    = bh % H_;
    const int b    = bh / H_;
    const size_t base  = (size_t)bh * L_ * D_;
    const size_t vbase = (size_t)bh * D_ * L_;
    const int qrow = q0 + w * 16 + c;      // this lane's q index (column of S^T)

    const float FMAX = expf(fminf(sml[h], MAXLOG)) + 8.0f;

    // Q B-fragments straight from global, held for the whole sweep.
    bf16x8 qf[2];
    qf[0] = *(const bf16x8*)&q[base + (size_t)qrow * D_ + quad * 8];
    qf[1] = *(const bf16x8*)&q[base + (size_t)qrow * D_ + 32 + quad * 8];

    // staging indices (coalesced b128)
    const int r0  = t >> 3,         c00 = (t & 7) * 8;
    const int r1  = (t + 256) >> 3, c01 = ((t + 256) & 7) * 8;

    const size_t brow = (size_t)qrow * L_ + 4 * quad;

    float l_acc = 0.f;
    f32x4 o[4];
    #pragma unroll
    for (int dt = 0; dt < 4; ++dt) o[dt] = (f32x4){0.f, 0.f, 0.f, 0.f};

    bf16x8 kreg[2], vreg[2];
    f32x4  bregA[4], bregB[4];

    // prologue: tile 0 -> regs -> LDS buf0; tile 1 -> regs; bias 0/1 -> regs
    kreg[0] = *(const bf16x8*)&k [base  + (size_t)r0 * D_ + c00];
    kreg[1] = *(const bf16x8*)&k [base  + (size_t)r1 * D_ + c01];
    vreg[0] = *(const bf16x8*)&vt[vbase + (size_t)r0 * L_ + c00];
    vreg[1] = *(const bf16x8*)&vt[vbase + (size_t)r1 * L_ + c01];
    #pragma unroll
    for (int s = 0; s < 4; ++s)
        bregA[s] = *(const f32x4*)&bias[brow + 16 * s];

    *(bf16x8*)&Ks0 [r0][c00] = kreg[0];
    *(bf16x8*)&Ks0 [r1][c01] = kreg[1];
    *(bf16x8*)&Vts0[r0][c00] = vreg[0];
    *(bf16x8*)&Vts0[r1][c01] = vreg[1];

    kreg[0] = *(const bf16x8*)&k [base  + (size_t)(64 + r0) * D_ + c00];
    kreg[1] = *(const bf16x8*)&k [base  + (size_t)(64 + r1) * D_ + c01];
    vreg[0] = *(const bf16x8*)&vt[vbase + (size_t)r0 * L_ + 64 + c00];
    vreg[1] = *(const bf16x8*)&vt[vbase + (size_t)r1 * L_ + 64 + c01];
    #pragma unroll
    for (int s = 0; s < 4; ++s)
        bregB[s] = *(const f32x4*)&bias[brow + 64 + 16 * s];
    __syncthreads();

// One 64-k tile: stage tile IT+1 from regs, prefetch tile IT+2 into regs,
// compute tile IT, single barrier at the end.
#define FSTEP(KS_C, VT_C, KS_N, VT_N, BC, IT) do {                               \
    if ((IT) + 1 < 32) {                                                         \
        *(bf16x8*)&KS_N [r0][c00] = kreg[0];                                     \
        *(bf16x8*)&KS_N [r1][c01] = kreg[1];                                     \
        *(bf16x8*)&VT_N [r0][c00] = vreg[0];                                     \
        *(bf16x8*)&VT_N [r1][c01] = vreg[1];                                     \
    }                                                                            \
    f32x4 st[4];                                                                 \
    _Pragma("unroll") for (int s = 0; s < 4; ++s) st[s] = BC[s];                 \
    if ((IT) + 2 < 32) {                                                         \
        const int kp = ((IT) + 2) * 64;                                          \
        kreg[0] = *(const bf16x8*)&k [base  + (size_t)(kp + r0) * D_ + c00];     \
        kreg[1] = *(const bf16x8*)&k [base  + (size_t)(kp + r1) * D_ + c01];     \
        vreg[0] = *(const bf16x8*)&vt[vbase + (size_t)r0 * L_ + kp + c00];       \
        vreg[1] = *(const bf16x8*)&vt[vbase + (size_t)r1 * L_ + kp + c01];       \
        _Pragma("unroll") for (int s = 0; s < 4; ++s)                            \
            BC[s] = *(const f32x4*)&bias[brow + kp + 16 * s];                    \
    }                                                                            \
    _Pragma("unroll") for (int ks = 0; ks < 2; ++ks)                             \
        _Pragma("unroll") for (int s = 0; s < 4; ++s) {                          \
            const bf16x8 kf = *(const bf16x8*)&KS_C[s*16 + c][ks*32 + quad*8];   \
            st[s] = __builtin_amdgcn_mfma_f32_16x16x32_bf16(kf, qf[ks], st[s], 0, 0, 0); \
        }                                                                        \
    bf16x4 pf[4];                                                                \
    _Pragma("unroll") for (int s = 0; s < 4; ++s)                                \
        _Pragma("unroll") for (int r = 0; r < 4; ++r) {                          \
            const float pv = __expf(st[s][r] - FMAX);                            \
            l_acc += pv;                                                         \
            pf[s][r] = (bf16)pv;                                                 \
        }                                                                        \
    _Pragma("unroll") for (int s = 0; s < 4; ++s)                                \
        _Pragma("unroll") for (int dt = 0; dt < 4; ++dt) {                       \
            const bf16x4 vfr = *(const bf16x4*)&VT_C[dt*16 + c][16*s + 4*quad];  \
            o[dt] = mfma16(vfr, pf[s], o[dt]);                                   \
        }                                                                        \
    __syncthreads();                                                             \
} while (0)

    for (int it = 0; it < 32; it += 2) {
        FSTEP(Ks0, Vts0, Ks1, Vts1, bregA, it);
        FSTEP(Ks1, Vts1, Ks0, Vts0, bregB, it + 1);
    }
#undef FSTEP

    // l: lane holds k-rows 4*quad+0..3 of every tile; reduce across quads.
    float rs = l_acc;
    rs += __shfl_xor(rs, 16);
    rs += __shfl_xor(rs, 32);
    const float linv = 1.0f / rs;

    const size_t obase = ((size_t)(b * L_ + qrow)) * C_ + h * 64;
    #pragma unroll
    for (int dt = 0; dt < 4; ++dt) {
        f16x4 hv, lv;
        #pragma unroll
        for (int r = 0; r < 4; ++r) {
            const float v = o[dt][r] * linv;
            hv[r] = (f16)v;
            lv[r] = (f16)(v - (float)hv[r]);
        }
        *(f16x4*)&aoh[obase + dt * 16 + 4 * quad] = hv;
        *(f16x4*)&aol[obase + dt * 16 + 4 * quad] = lv;
    }
}

// ---------------------------------------------------------------------------
// Kernel 3: projection GEMM v3 (R15 — best measured): f16 2-MFMA path,
//   BM=128 BN=64, grid 32x12. A = f16 hi/lo pair, W = single f16.
// ---------------------------------------------------------------------------
__global__ __launch_bounds__(256) void proj_mfma(
    const f16* __restrict__ Ahg, const f16* __restrict__ Alg,
    const f16* __restrict__ Wfg,
    const float* __restrict__ bias, float* __restrict__ outp)
{
    __shared__ __align__(16) f16 Ah[128][64];   // 16 KB
    __shared__ __align__(16) f16 Al[128][64];   // 16 KB
    __shared__ __align__(16) f16 Wf[64][64];    //  8 KB

    const int t    = threadIdx.x;
    const int w    = t >> 6;
    const int lane = t & 63;
    const int quad = lane >> 4;
    const int c    = lane & 15;
    const int m0   = blockIdx.x * 128;
    const int n0   = blockIdx.y * 64;

    const int sr = t >> 3;           // 0..31
    const int sc = t & 7;
    const int sx = sc ^ (sr & 7);

    f32x4 acc[2][4];
    #pragma unroll
    for (int mt = 0; mt < 2; ++mt)
        #pragma unroll
        for (int nt = 0; nt < 4; ++nt) acc[mt][nt] = (f32x4){0.f,0.f,0.f,0.f};

    for (int kt = 0; kt < C_; kt += 64) {
        __syncthreads();
        #pragma unroll
        for (int p = 0; p < 4; ++p) {
            const size_t ga = (size_t)(m0 + 32 * p + sr) * C_ + kt + 8 * sx;
            const int    lo = (p * 256 + t) * 16;
            stage16(&Ahg[ga], (char*)&Ah[0][0] + lo);
            stage16(&Alg[ga], (char*)&Al[0][0] + lo);
        }
        #pragma unroll
        for (int p = 0; p < 2; ++p) {
            const size_t gb = (size_t)(n0 + 32 * p + sr) * C_ + kt + 8 * sx;
            const int    lo = (p * 256 + t) * 16;
            stage16(&Wfg[gb], (char*)&Wf[0][0] + lo);
        }
        __syncthreads();

        #pragma unroll
        for (int ks = 0; ks < 2; ++ks) {
            const int rchunk = ((4 * ks + quad) ^ (c & 7)) * 16;
            f16x8 wf[4];
            #pragma unroll
            for (int nt = 0; nt < 4; ++nt)
                wf[nt] = *(const f16x8*)((const char*)&Wf[0][0]
                         + (size_t)(nt * 16 + c) * 128 + rchunk);
            #pragma unroll
            for (int mt = 0; mt < 2; ++mt) {
                const f16x8 ah = *(const f16x8*)((const char*)&Ah[0][0]
                                 + (size_t)(w * 32 + mt * 16 + c) * 128 + rchunk);
                const f16x8 al = *(const f16x8*)((const char*)&Al[0][0]
                                 + (size_t)(w * 32 + mt * 16 + c) * 128 + rchunk);
                #pragma unroll
                for (int nt = 0; nt < 4; ++nt) {
                    acc[mt][nt] = __builtin_amdgcn_mfma_f32_16x16x32_f16(ah, wf[nt], acc[mt][nt], 0, 0, 0);
                    acc[mt][nt] = __builtin_amdgcn_mfma_f32_16x16x32_f16(al, wf[nt], acc[mt][nt], 0, 0, 0);
                }
            }
        }
    }

    #pragma unroll
    for (int mt = 0; mt < 2; ++mt)
        #pragma unroll
        for (int nt = 0; nt < 4; ++nt) {
            const int col = n0 + nt * 16 + c;
            const float bb = bias[col];
            #pragma unroll
            for (int reg = 0; reg < 4; ++reg) {
                const int row = m0 + w * 32 + mt * 16 + quad * 4 + reg;
                outp[(size_t)row * C_ + col] = acc[mt][nt][reg] + bb;
            }
        }
}

// ---------------------------------------------------------------------------
extern "C" void kernel_launch(void* const* d_in, const int* in_sizes, int n_in,
                              void* d_out, int out_size, void* d_ws, size_t ws_size,
                              hipStream_t stream)
{
    const float* x         = (const float*)d_in[0];
    const float* attn_bias = (const float*)d_in[1];
    const float* W_qkv     = (const float*)d_in[2];
    const float* b_qkv     = (const float*)d_in[3];
    const float* sml       = (const float*)d_in[4];
    const float* W_proj    = (const float*)d_in[5];
    const float* b_proj    = (const float*)d_in[6];
    float* out = (float*)d_out;

    // ws layout (2-byte elements): qb,kb,vtb | aoh,aol (f16) | Wf (f16) | pad | xb | wqb
    bf16* qb  = (bf16*)d_ws;
    bf16* kb  = qb  + SZ_;
    bf16* vtb = kb  + SZ_;
    f16*  aoh = (f16*)(vtb + SZ_);
    f16*  aol = aoh + MC_;
    f16*  Wf  = aol + MC_;
    bf16* xb  = (bf16*)(Wf + 2 * WP_);   // (second WP_ slot unused, layout stability)
    bf16* wqb = xb  + MC_;

    // 0) fused prep: cvt x/W_qkv to bf16, W_proj to single f16
    prep<<<2048, 256, 0, stream>>>(
        (const float4*)x, (const float4*)W_qkv, (const float4*)W_proj,
        xb, wqb, Wf);

    // 1) QKV GEMM v2: 128x128 tile (2 heads/block), grid 32x18
    qkv_mfma<<<dim3(M_ / 128, (3 * C_) / 128), 256, 0, stream>>>(
        xb, wqb, b_qkv, sml, qb, kb, vtb);

    // 2) flash attention (v7 structure; f16 hi/lo epilogue)
    flash_mfma<<<dim3(L_ / 64, B_ * H_), 256, 0, stream>>>(
        qb, kb, vtb, attn_bias, sml, aoh, aol);

    // 3) projection GEMM v3 (R15 best): f16 2-MFMA, BM=128 BN=64, grid 32x12
    proj_mfma<<<dim3(M_ / 128, C_ / 64), 256, 0, stream>>>(
        aoh, aol, Wf, b_proj, out);
}